// Round 9
// baseline (86.847 us; speedup 1.0000x reference)
//
#include <hip/hip_runtime.h>

#define NQ 10
#define NL 3

typedef float v2f __attribute__((ext_vector_type(2)));

__device__ __forceinline__ int   f2i(float v) { union { float f; int i; } u; u.f = v; return u.i; }
__device__ __forceinline__ float i2f(int v)   { union { int i; float f; } u; u.i = v; return u.f; }
// uniformize a wave-uniform float into SGPR (R1-proven)
__device__ __forceinline__ float uf(float v) {
    return i2f(__builtin_amdgcn_readfirstlane(f2i(v)));
}

// ---- R1-proven packed-f32 complex helpers (these exact asm forms passed
// R1/R4/R5 — no new asm in this round, per the R2/R6 lesson) ----
__device__ __forceinline__ v2f cmul(v2f a, v2f b) {
    v2f d;
    asm("v_pk_mul_f32 %0, %1, %2 op_sel:[0,0] op_sel_hi:[0,1]"
        : "=v"(d) : "v"(a), "v"(b));                       // (ax*bx, ax*by)
    asm("v_pk_fma_f32 %0, %1, %2, %0 op_sel:[1,1,0] op_sel_hi:[1,0,1] neg_lo:[0,1,0]"
        : "+v"(d) : "v"(a), "v"(b));                       // (+= -ay*by, += ay*bx)
    return d;
}
__device__ __forceinline__ v2f pk_ab(v2f A, v2f B, v2f cs) {
    v2f d;
    asm("v_pk_mul_f32 %0, %1, %2 op_sel:[0,1] op_sel_hi:[1,1]"
        : "=v"(d) : "v"(B), "v"(cs));                      // (B.x*s, B.y*s)
    asm("v_pk_fma_f32 %0, %1, %2, %0 op_sel:[0,0,0] op_sel_hi:[1,0,1]"
        : "+v"(d) : "v"(A), "v"(cs));                      // += (A.x*c, A.y*c)
    return d;
}
__device__ __forceinline__ v2f pk_ab_n(v2f A, v2f B, v2f cs) {
    v2f d;
    asm("v_pk_mul_f32 %0, %1, %2 op_sel:[0,1] op_sel_hi:[1,1] neg_lo:[1,0] neg_hi:[1,0]"
        : "=v"(d) : "v"(B), "v"(cs));                      // (-B.x*s, -B.y*s)
    asm("v_pk_fma_f32 %0, %1, %2, %0 op_sel:[0,0,0] op_sel_hi:[1,0,1]"
        : "+v"(d) : "v"(A), "v"(cs));
    return d;
}

template<int C> __device__ __forceinline__ int dppm(int v) {
    return __builtin_amdgcn_mov_dpp(v, C, 0xF, 0xF, false);
}

// lane exchange by xor mask LM — R1-proven routing
template<int LM>
__device__ __forceinline__ v2f xlane(v2f v, int baddr) {
    if constexpr (LM == 0) return v;
    int x = f2i(v.x), y = f2i(v.y);
    if constexpr (LM == 1)       { x = dppm<177>(x); y = dppm<177>(y); }
    else if constexpr (LM == 2)  { x = dppm<78>(x);  y = dppm<78>(y); }
    else if constexpr (LM == 3)  { x = dppm<27>(x);  y = dppm<27>(y); }
    else if constexpr (LM < 32) {
        constexpr int off = (LM << 10) | 0x1F;   // BitMode xor
        x = __builtin_amdgcn_ds_swizzle(x, off);
        y = __builtin_amdgcn_ds_swizzle(y, off);
    } else {
        x = __builtin_amdgcn_ds_bpermute(baddr, x);
        y = __builtin_amdgcn_ds_bpermute(baddr, y);
    }
    return (v2f){ i2f(x), i2f(y) };
}

// ---- R9: state split across 2 waves (slot bit3 = wave id) for 8 waves/SIMD.
// Masks UNCHANGED (no algebra re-derivation); global slot gj = (wid<<3)|j.
// Slot-parity factorization: popc(gj&RL) = popc(j&(RL&7)) ^ (wid & RL>>3),
// the wid part folded into the lane-parity select (exact). Cross-wave gates
// (JM bit3 set: idx 12,13,21,23) exchange via LDS + barrier; partner =
// xch[wid^1][j^(JM&7)][lane^LM]. ----
template<int MASK, int RMASK, bool CROSS>
__device__ __forceinline__ void agate(v2f (&a)[8], float4 r0, float4 r1,
                                      float cq, float sq, int lane, int wid,
                                      v2f (*xch)[8][64])
{
    constexpr int LM  = (MASK >> 4) & 63;
    constexpr int JM  = MASK & 15;
    constexpr int JML = JM & 7;
    constexpr int RH  = (RMASK >> 4) & 63;
    constexpr int RL  = RMASK & 15;
    constexpr int RL3 = (RL >> 3) & 1;
    constexpr int RLL = RL & 7;

    // phase 1: partner values
    v2f o[8];
    if constexpr (!CROSS) {
        const int baddr = ((lane ^ LM) << 2);
        #pragma unroll
        for (int j = 0; j < 8; ++j) o[j] = xlane<LM>(a[j ^ JML], baddr);
    } else {
        #pragma unroll
        for (int j = 0; j < 8; ++j) xch[wid][j][lane] = a[j];
        __syncthreads();
        #pragma unroll
        for (int j = 0; j < 8; ++j) o[j] = xch[wid ^ 1][j ^ JML][lane ^ LM];
        __syncthreads();   // buffer safe for reuse by later gates
    }

    // fuse Rot * RY(c,s): R1 form
    const v2f vcs = { cq, sq };
    const v2f r0a = { r0.x, r0.y }, r0b = { r0.z, r0.w };
    const v2f r1a = { r1.x, r1.y }, r1b = { r1.z, r1.w };
    const v2f g00 = pk_ab  (r0a, r0b, vcs);
    const v2f g01 = pk_ab_n(r0b, r0a, vcs);
    const v2f g10 = pk_ab  (r1a, r1b, vcs);
    const v2f g11 = pk_ab_n(r1b, r1a, vcs);

    const bool lp0 = (RH != 0) && (__popc(lane & RH) & 1);
    const bool lpw = lp0 != ((RL3 != 0) && (wid != 0));   // wid folds in wave bit
    const v2f A0 = lpw ? g11 : g00;
    const v2f B0 = lpw ? g10 : g01;
    const v2f A1 = lpw ? g00 : g11;
    const v2f B1 = lpw ? g01 : g10;

    // phase 2: new = A (x) a + B (x) o (R1-proven asm body), 8 local slots
#define QNN_F(J) { constexpr int SP_ = __builtin_popcount((J) & RLL) & 1;     \
    const v2f CA = SP_ ? A1 : A0;                                             \
    const v2f CB = SP_ ? B1 : B0;                                             \
    const v2f av = a[J]; const v2f ov = o[J];                                 \
    v2f d;                                                                    \
    asm("v_pk_mul_f32 %0, %1, %2 op_sel:[0,0] op_sel_hi:[0,1]"                \
        : "=v"(d) : "v"(CA), "v"(av));          /* (Ar*ar, Ar*ai) */          \
    asm("v_pk_fma_f32 %0, %1, %2, %0 op_sel:[1,1,0] op_sel_hi:[1,0,1] neg_lo:[0,1,0]" \
        : "+v"(d) : "v"(CA), "v"(av));          /* (-Ai*ai, +Ai*ar) */        \
    asm("v_pk_fma_f32 %0, %1, %2, %0 op_sel:[0,0,0] op_sel_hi:[0,1,1]"        \
        : "+v"(d) : "v"(CB), "v"(ov));          /* (+Br*pr, +Br*pi) */        \
    asm("v_pk_fma_f32 %0, %1, %2, %0 op_sel:[1,1,0] op_sel_hi:[1,0,1] neg_lo:[0,1,0]" \
        : "+v"(d) : "v"(CB), "v"(ov));          /* (-Bi*pi, +Bi*pr) */        \
    a[J] = d; }
    QNN_F(0) QNN_F(1) QNN_F(2) QNN_F(3) QNN_F(4) QNN_F(5) QNN_F(6) QNN_F(7)
#undef QNN_F
}

__global__ __launch_bounds__(128, 8)
void qnn_kernel(const float* __restrict__ x, const float* __restrict__ w,
                float* __restrict__ out)
{
    __shared__ float4 rotL[NL * NQ][2];   // (R00,R01) | (R10,R11)
    __shared__ v2f    xch[2][8][64];      // 8 KB cross-wave exchange buffer

    const int t    = threadIdx.x;
    const int lane = t & 63;
    const int wid  = t >> 6;              // slot bit3
    const int b    = blockIdx.x;          // one element per 2-wave block

    if (t < NL * NQ) {
        const float* wp = w + t * 3;
        float phi = wp[0], th = wp[1], om = wp[2];
        float ct = cosf(th * 0.5f), st = sinf(th * 0.5f);
        float ap = (phi + om) * 0.5f, am = (phi - om) * 0.5f;
        float cap = cosf(ap), sap = sinf(ap);
        float cam = cosf(am), sam = sinf(am);
        rotL[t][0] = make_float4(cap * ct, -sap * ct, -cam * st, -sam * st);
        rotL[t][1] = make_float4(cam * st, -sam * st,  cap * ct,  sap * ct);
    }
    __syncthreads();

    // ---- per-batch RY cos/sin (uniform per block -> SGPR) ----
    const float* xb = x + (size_t)b * NQ;
    float c_[NQ], s_[NQ];
    #pragma unroll
    for (int q = 0; q < NQ; ++q) {
        float xv = xb[q] * 0.5f;
        c_[q] = uf(__cosf(xv));
        s_[q] = uf(__sinf(xv));
    }

    // ---- layer 1 analytic: product state; this wave's 8 slots ----
    v2f c0[4], c1[4];
    v2f Ln = {1.f, 0.f};
    #pragma unroll
    for (int q = 0; q < NQ; ++q) {
        float4 r0 = rotL[q][0], r1 = rotL[q][1];
        const v2f vcs = { c_[q], s_[q] };
        const v2f r0a = { r0.x, r0.y }, r0b = { r0.z, r0.w };
        const v2f r1a = { r1.x, r1.y }, r1b = { r1.z, r1.w };
        v2f g0 = pk_ab(r0a, r0b, vcs);
        v2f g1 = pk_ab(r1a, r1b, vcs);
        if (q < 4) { c0[q] = g0; c1[q] = g1; }
        else {
            v2f gg = ((lane >> (q - 4)) & 1) ? g1 : g0;
            Ln = (q == 4) ? gg : cmul(Ln, gg);
        }
    }
    v2f S01[4], SH[4];
    #pragma unroll
    for (int j = 0; j < 4; ++j)
        S01[j] = cmul((j & 1) ? c1[0] : c0[0], (j & 2) ? c1[1] : c0[1]);
    #pragma unroll
    for (int h = 0; h < 4; ++h)
        SH[h] = cmul(cmul((h & 1) ? c1[2] : c0[2], (h & 2) ? c1[3] : c0[3]), Ln);
    v2f a[8];
    #pragma unroll
    for (int j = 0; j < 8; ++j)
        a[j] = cmul(S01[j & 3], SH[(wid << 1) | (j >> 2)]);   // global slot bits

    // ---- layers 2..3 (masks verified R2-R11; CROSS = JM bit3) ----
#define GATE(IDX, Q, MASK, RMASK)                                             \
    agate<MASK, RMASK, ((MASK & 8) != 0)>(a, rotL[IDX][0], rotL[IDX][1],      \
                                          c_[Q], s_[Q], lane, wid, xch);
    GATE(10, 0, 0x003, 0x3FE)  GATE(11, 1, 0x006, 0x003)
    GATE(12, 2, 0x00C, 0x007)  GATE(13, 3, 0x018, 0x00F)
    GATE(14, 4, 0x030, 0x01F)  GATE(15, 5, 0x060, 0x03F)
    GATE(16, 6, 0x0C0, 0x07F)  GATE(17, 7, 0x180, 0x0FF)
    GATE(18, 8, 0x300, 0x1FF)  GATE(19, 9, 0x203, 0x3FF)
    GATE(20, 0, 0x005, 0x2AB)  GATE(21, 1, 0x00A, 0x3FD)
    GATE(22, 2, 0x014, 0x3FA)  GATE(23, 3, 0x028, 0x3F5)
    GATE(24, 4, 0x050, 0x3EA)  GATE(25, 5, 0x0A0, 0x3D5)
    GATE(26, 6, 0x140, 0x3AA)  GATE(27, 7, 0x280, 0x355)
    GATE(28, 8, 0x103, 0x2AA)  GATE(29, 9, 0x206, 0x155)
#undef GATE

    // ---- probabilities + WH: bits 0-2 in-wave, bit 3 via LDS ----
    float P[8];
    #pragma unroll
    for (int j = 0; j < 8; ++j)
        P[j] = fmaf(a[j].x, a[j].x, a[j].y * a[j].y);
    #pragma unroll
    for (int bit = 0; bit < 3; ++bit) {
        #pragma unroll
        for (int j = 0; j < 8; ++j)
            if (!(j & (1 << bit))) {
                int k = j | (1 << bit);
                float u = P[j], v = P[k];
                P[j] = u + v;
                P[k] = u - v;
            }
    }
    #pragma unroll
    for (int j = 0; j < 8; ++j) xch[wid][j][lane].x = P[j];
    __syncthreads();
    #pragma unroll
    for (int j = 0; j < 8; ++j) {
        float po = xch[wid ^ 1][j][lane].x;
        P[j] = (wid == 0) ? (P[j] + po) : (po - P[j]);   // WH bit3
    }

    const int bp32 = ((lane ^ 32) << 2);
#define MEAS(Q, RM)                                                           \
    { constexpr int RH_ = ((RM) >> 4) & 63;                                   \
      constexpr int RL_ = (RM) & 15;                                          \
      float v = P[RL_ & 7];                                                   \
      if (__popc(lane & RH_) & 1) v = -v;                                     \
      v += i2f(dppm<177>(f2i(v)));                 /* xor1  */                \
      v += i2f(dppm<78>(f2i(v)));                  /* xor2  */                \
      v += i2f(dppm<321>(dppm<27>(f2i(v))));       /* xor4 = 7^3 */           \
      v += i2f(dppm<320>(dppm<321>(f2i(v))));      /* xor8 = 15^7 */          \
      v += i2f(__builtin_amdgcn_ds_swizzle(f2i(v), (16 << 10) | 0x1F));       \
      v += i2f(__builtin_amdgcn_ds_bpermute(bp32, f2i(v)));                   \
      if (wid == (RL_ >> 3) && lane == (Q)) out[b * NQ + (Q)] = v; }
    MEAS(0, 0x0CD) MEAS(1, 0x156) MEAS(2, 0x2AC) MEAS(3, 0x159)
    MEAS(4, 0x2B3) MEAS(5, 0x166) MEAS(6, 0x2CC) MEAS(7, 0x199)
    MEAS(8, 0x333) MEAS(9, 0x266)
#undef MEAS
}

extern "C" void kernel_launch(void* const* d_in, const int* in_sizes, int n_in,
                              void* d_out, int out_size, void* d_ws, size_t ws_size,
                              hipStream_t stream) {
    const float* x = (const float*)d_in[0];   // (4096, 10) f32
    const float* w = (const float*)d_in[1];   // (3, 10, 3) f32
    float* out = (float*)d_out;               // (4096, 10) f32
    const int B = in_sizes[0] / NQ;           // 4096
    qnn_kernel<<<B, 128, 0, stream>>>(x, w, out);
}